// Round 1
// 206.979 us; speedup vs baseline: 1.0831x; 1.0831x over previous
//
#include <hip/hip_runtime.h>

// ---------------------------------------------------------------------------
// CapsNet dynamic routing, fully fused, fp32.
//   x: [B=64, I=8192, N=8]   W: [I=8192, J=8, N=8, M=16]   out: [B, J=8, M=16]
//
// b_logits after t iters = dot(sum_{t'<=t} v_{t'}, u_hat); carry only
// vsum[B,J,M] between passes, recompute u_hat per pass (x,W are L3-resident).
//
// Pass kernel: 256 blocks x 1024 threads (16 waves/CU, 4 waves/SIMD — the
// previous 512-thread version was 1 block/CU = 2 waves/SIMD, latency-bound at
// 29% VALUBusy). Thread = (bg, j, mq): covers b in {bg, bg+32}, one j, m-quad.
// Register-blocking 2 b's per thread halves LDS reads per FMA (8 ds_read_b128
// feed 128 FMAs) and doubles ILP. W[i] staged in LDS (8 i per barrier, padded
// j-stride). Softmax skips max-subtract: logits = dot(vsum,u), |logit| <~ 1.
// Reduce kernel: coalesced 256-partial sum + squash; first call writes vsum
// (no memset dispatch needed).
// ---------------------------------------------------------------------------

#define BB      64
#define ICAPS   8192
#define NDIM    8
#define JCAPS   8
#define MDIM    16
#define NBLK    256
#define ICHUNK  (ICAPS / NBLK)        // 32
#define IG      8                     // i's staged per barrier
#define NSTAGE  (ICHUNK / IG)         // 4
#define WJ_STRIDE (NDIM * MDIM + 4)   // 132 floats: pad to spread LDS banks
#define WI_STRIDE (JCAPS * WJ_STRIDE) // 1056 floats per i
#define S_ELEMS  (BB * JCAPS * MDIM)  // 8192 floats per s / vsum / out

// MODE 0: uniform c = 1/8 (softmax of zero logits)
// MODE 1: c = softmax_j( dot(vsum[b,j,:], u_hat[b,i,j,:]) )
template <int MODE>
__global__ __launch_bounds__(1024, 4) void caps_pass_kernel(
    const float* __restrict__ x, const float* __restrict__ W,
    const float* __restrict__ vsum, float* __restrict__ partial)
{
    __shared__ float Wlds[IG * WI_STRIDE];   // 33,792 B

    const int tid = threadIdx.x;             // 0..1023
    const int mq  = tid & 3;                 // m-quad: m in [mq*4, mq*4+4)
    const int j   = (tid >> 2) & 7;          // out-cap
    const int bg  = tid >> 5;                // 0..31
    const int b0  = bg;
    const int b1  = bg + 32;
    const int blk = blockIdx.x;
    const int i0  = blk * ICHUNK;

    float s0[4] = {0.f, 0.f, 0.f, 0.f};
    float s1[4] = {0.f, 0.f, 0.f, 0.f};

    float v0[4], v1[4];
    if (MODE == 1) {
        const float4 a = *(const float4*)&vsum[(b0 * JCAPS + j) * MDIM + mq * 4];
        v0[0] = a.x; v0[1] = a.y; v0[2] = a.z; v0[3] = a.w;
        const float4 c = *(const float4*)&vsum[(b1 * JCAPS + j) * MDIM + mq * 4];
        v1[0] = c.x; v1[1] = c.y; v1[2] = c.z; v1[3] = c.w;
    }

    for (int st = 0; st < NSTAGE; ++st) {
        // ---- stage W for IG i's into LDS (each thread: 8 contiguous floats) ----
        {
            const int iL  = tid >> 7;        // 0..7
            const int rem = tid & 127;       // 8-float chunk within the i
            const float4* src = (const float4*)(W + (size_t)(i0 + st * IG + iL) * 1024
                                                  + rem * 8);
            float4* dst = (float4*)&Wlds[iL * WI_STRIDE + (rem >> 4) * WJ_STRIDE
                                         + (rem & 15) * 8];
            dst[0] = src[0]; dst[1] = src[1];
        }
        __syncthreads();

        #pragma unroll
        for (int ii = 0; ii < IG; ++ii) {
            const int i = i0 + st * IG + ii;
            const float4 xa0 = *(const float4*)&x[((size_t)b0 * ICAPS + i) * NDIM];
            const float4 xb0 = *(const float4*)&x[((size_t)b0 * ICAPS + i) * NDIM + 4];
            const float4 xa1 = *(const float4*)&x[((size_t)b1 * ICAPS + i) * NDIM];
            const float4 xb1 = *(const float4*)&x[((size_t)b1 * ICAPS + i) * NDIM + 4];
            const float xs0[8] = {xa0.x, xa0.y, xa0.z, xa0.w, xb0.x, xb0.y, xb0.z, xb0.w};
            const float xs1[8] = {xa1.x, xa1.y, xa1.z, xa1.w, xb1.x, xb1.y, xb1.z, xb1.w};

            // u_hat fragments for (b0,j,mq*4..+4) and (b1,j,mq*4..+4)
            float u0[4] = {0.f, 0.f, 0.f, 0.f};
            float u1[4] = {0.f, 0.f, 0.f, 0.f};
            const float* wb = &Wlds[ii * WI_STRIDE + j * WJ_STRIDE + mq * 4];
            #pragma unroll
            for (int n = 0; n < NDIM; ++n) {
                const float4 wq = *(const float4*)&wb[n * MDIM];
                u0[0] += xs0[n] * wq.x; u0[1] += xs0[n] * wq.y;
                u0[2] += xs0[n] * wq.z; u0[3] += xs0[n] * wq.w;
                u1[0] += xs1[n] * wq.x; u1[1] += xs1[n] * wq.y;
                u1[2] += xs1[n] * wq.z; u1[3] += xs1[n] * wq.w;
            }

            if (MODE == 0) {
                #pragma unroll
                for (int m = 0; m < 4; ++m) { s0[m] += u0[m]; s1[m] += u1[m]; }
            } else {
                // partial logit over this m-quad, then reduce over mq lanes (bits 0,1)
                float lp0 = u0[0] * v0[0] + u0[1] * v0[1] + u0[2] * v0[2] + u0[3] * v0[3];
                float lp1 = u1[0] * v1[0] + u1[1] * v1[1] + u1[2] * v1[2] + u1[3] * v1[3];
                lp0 += __shfl_xor(lp0, 1);  lp0 += __shfl_xor(lp0, 2);
                lp1 += __shfl_xor(lp1, 1);  lp1 += __shfl_xor(lp1, 2);
                // softmax over j (lanes bits 2,3,4). |logit| <~ 1 -> no max-subtract.
                const float e0 = __expf(lp0);
                const float e1 = __expf(lp1);
                float d0 = e0, d1 = e1;
                d0 += __shfl_xor(d0, 4); d0 += __shfl_xor(d0, 8); d0 += __shfl_xor(d0, 16);
                d1 += __shfl_xor(d1, 4); d1 += __shfl_xor(d1, 8); d1 += __shfl_xor(d1, 16);
                const float c0 = e0 * __builtin_amdgcn_rcpf(d0);
                const float c1 = e1 * __builtin_amdgcn_rcpf(d1);
                #pragma unroll
                for (int m = 0; m < 4; ++m) { s0[m] += c0 * u0[m]; s1[m] += c1 * u1[m]; }
            }
        }
        __syncthreads();
    }

    // ---- store block-partial s: partial[blk][b][j][m] ----
    const float sc = (MODE == 0) ? 0.125f : 1.0f;
    float* pp = partial + (size_t)blk * S_ELEMS;
    float4 o0, o1;
    o0.x = s0[0] * sc; o0.y = s0[1] * sc; o0.z = s0[2] * sc; o0.w = s0[3] * sc;
    o1.x = s1[0] * sc; o1.y = s1[1] * sc; o1.z = s1[2] * sc; o1.w = s1[3] * sc;
    *(float4*)&pp[(b0 * JCAPS + j) * MDIM + mq * 4] = o0;
    *(float4*)&pp[(b1 * JCAPS + j) * MDIM + mq * 4] = o1;
}

// Sum 256 partials -> s[b,j,m]; v = squash(s).
// OP 0: vsum = v (first pass, avoids memset)   OP 1: vsum += v   OP 2: out = v
template <int OP>
__global__ __launch_bounds__(256) void caps_reduce_kernel(
    const float* __restrict__ partial, float* __restrict__ vsum, float* __restrict__ out)
{
    __shared__ float sd[256];
    const int bo  = blockIdx.x;     // 0..127, each block covers 64 outputs
    const int tid = threadIdx.x;
    const int kg  = tid >> 6;       // 0..3  partial-group (64 partials each)
    const int tl  = tid & 63;       // output-within-block; lanes contiguous in t
    const int t   = bo * 64 + tl;   // global output index (= b*128 + j*16 + m)

    float a0 = 0.f, a1 = 0.f, a2 = 0.f, a3 = 0.f;
    const float* p = partial + (size_t)kg * 64 * S_ELEMS + t;
    #pragma unroll
    for (int k = 0; k < 64; k += 4) {
        a0 += p[(size_t)(k + 0) * S_ELEMS];
        a1 += p[(size_t)(k + 1) * S_ELEMS];
        a2 += p[(size_t)(k + 2) * S_ELEMS];
        a3 += p[(size_t)(k + 3) * S_ELEMS];
    }
    sd[tid] = (a0 + a1) + (a2 + a3);
    __syncthreads();

    if (tid < 64) {
        const float s = (sd[tid] + sd[64 + tid]) + (sd[128 + tid] + sd[192 + tid]);
        // squash: sn over the 16 m's of this (b,j) — lanes grouped by 16
        float sn = s * s;
        sn += __shfl_xor(sn, 1);
        sn += __shfl_xor(sn, 2);
        sn += __shfl_xor(sn, 4);
        sn += __shfl_xor(sn, 8);
        const float v = s * sqrtf(sn) / (1.f + sn);
        const int tt = bo * 64 + tid;
        if (OP == 2)      out[tt]   = v;
        else if (OP == 1) vsum[tt] += v;
        else              vsum[tt]  = v;
    }
}

extern "C" void kernel_launch(void* const* d_in, const int* in_sizes, int n_in,
                              void* d_out, int out_size, void* d_ws, size_t ws_size,
                              hipStream_t stream)
{
    const float* x = (const float*)d_in[0];   // [64, 8192, 8]
    const float* W = (const float*)d_in[1];   // [8192, 8, 8, 16]
    float* out = (float*)d_out;               // [64, 8, 16]

    float* partial = (float*)d_ws;                              // 256 * 8192 floats = 8 MB
    float* vsum    = partial + (size_t)NBLK * S_ELEMS;          // 8192 floats

    // pass 1: c uniform
    caps_pass_kernel<0><<<NBLK, 1024, 0, stream>>>(x, W, vsum, partial);
    caps_reduce_kernel<0><<<128, 256, 0, stream>>>(partial, vsum, nullptr);  // vsum = v1
    // pass 2: logits = dot(v1, u_hat)
    caps_pass_kernel<1><<<NBLK, 1024, 0, stream>>>(x, W, vsum, partial);
    caps_reduce_kernel<1><<<128, 256, 0, stream>>>(partial, vsum, nullptr);  // vsum = v1+v2
    // pass 3 (final): logits = dot(v1+v2, u_hat), output squash
    caps_pass_kernel<1><<<NBLK, 1024, 0, stream>>>(x, W, vsum, partial);
    caps_reduce_kernel<2><<<128, 256, 0, stream>>>(partial, vsum, out);
}

// Round 2
// 192.168 us; speedup vs baseline: 1.1666x; 1.0771x over previous
//
#include <hip/hip_runtime.h>

// ---------------------------------------------------------------------------
// CapsNet dynamic routing, fully fused, fp32.
//   x: [B=64, I=8192, N=8]   W: [I=8192, J=8, N=8, M=16]   out: [B, J=8, M=16]
//
// b_logits after t iters = dot(sum_{t'<=t} v_{t'}, u_hat); carry only
// vsum[B,J,M] between passes, recompute u_hat per pass (x,W are L3-resident).
//
// Pass kernel: 256 blocks x 1024 threads. Thread = (b, j, i-parity): owns the
// FULL 16-m row of u_hat for one (b,j). Consequences vs the (bg,j,mq) map:
//   * LDS reads are conflict-free: per phase, 8 distinct j-rows start at
//     banks {0,4,..,28} (WJ_STRIDE=132 -> 4j mod 32), 8-fold b-broadcast free.
//     (previous map: 32 distinct addrs/instr -> 8.6M bank-conflict cycles)
//   * logit dot over m is in-register; softmax j-reduce is 3 shfl_xor (1,2,4)
//     instead of 10 (xor 1,2 are DPP quad-perms). 1 exp per (b,i) not 2.
//   * 4x fewer x-load VMEM instructions.
// i-parity halves combine once per block through LDS (reusing Wlds).
// Softmax skips max-subtract: logits = dot(vsum,u_hat), |logit| << 10.
// Reduce kernel: coalesced 256-partial sum + squash; first call writes vsum.
// ---------------------------------------------------------------------------

#define BB      64
#define ICAPS   8192
#define NDIM    8
#define JCAPS   8
#define MDIM    16
#define NBLK    256
#define ICHUNK  (ICAPS / NBLK)        // 32
#define IG      8                     // i's staged per barrier
#define NSTAGE  (ICHUNK / IG)         // 4
#define WJ_STRIDE (NDIM * MDIM + 4)   // 132 floats: pad -> j-rows spread banks
#define WI_STRIDE (JCAPS * WJ_STRIDE) // 1056 floats per i
#define S_ELEMS  (BB * JCAPS * MDIM)  // 8192 floats per s / vsum / out

// MODE 0: uniform c = 1/8 (softmax of zero logits)
// MODE 1: c = softmax_j( dot(vsum[b,j,:], u_hat[b,i,j,:]) )
template <int MODE>
__global__ __launch_bounds__(1024, 4) void caps_pass_kernel(
    const float* __restrict__ x, const float* __restrict__ W,
    const float* __restrict__ vsum, float* __restrict__ partial)
{
    __shared__ float Wlds[IG * WI_STRIDE];   // 33,792 B; reused for final reduce

    const int tid  = threadIdx.x;            // 0..1023
    const int j    = tid & 7;                // out-cap (lane bits 0-2)
    const int b    = (tid >> 3) & 63;        // batch   (lane bits 3-5 + wave)
    const int isub = tid >> 9;               // 0/1: i-parity within a stage
    const int blk  = blockIdx.x;
    const int i0   = blk * ICHUNK;

    float s[MDIM];
    #pragma unroll
    for (int m = 0; m < MDIM; ++m) s[m] = 0.f;

    float v[MDIM];
    if (MODE == 1) {
        #pragma unroll
        for (int q = 0; q < 4; ++q) {
            const float4 a = *(const float4*)&vsum[(b * JCAPS + j) * MDIM + q * 4];
            v[q * 4 + 0] = a.x; v[q * 4 + 1] = a.y;
            v[q * 4 + 2] = a.z; v[q * 4 + 3] = a.w;
        }
    }

    for (int st = 0; st < NSTAGE; ++st) {
        // ---- stage W for IG i's into LDS (each thread: 8 contiguous floats) ----
        {
            const int iL  = tid >> 7;        // 0..7
            const int rem = tid & 127;       // 8-float chunk within the i
            const float4* src = (const float4*)(W + (size_t)(i0 + st * IG + iL) * 1024
                                                  + rem * 8);
            float4* dst = (float4*)&Wlds[iL * WI_STRIDE + (rem >> 4) * WJ_STRIDE
                                         + (rem & 15) * 8];
            dst[0] = src[0]; dst[1] = src[1];
        }
        __syncthreads();

        #pragma unroll
        for (int t = 0; t < IG / 2; ++t) {
            const int ii = t * 2 + isub;     // interleave parities
            const int i  = i0 + st * IG + ii;
            const float4 xa = *(const float4*)&x[((size_t)b * ICAPS + i) * NDIM];
            const float4 xb = *(const float4*)&x[((size_t)b * ICAPS + i) * NDIM + 4];
            const float xs[8] = {xa.x, xa.y, xa.z, xa.w, xb.x, xb.y, xb.z, xb.w};

            // u_hat full m-row for (b,i,j): conflict-free ds_read_b128 stream
            float u[MDIM];
            #pragma unroll
            for (int m = 0; m < MDIM; ++m) u[m] = 0.f;
            const float* wb = &Wlds[ii * WI_STRIDE + j * WJ_STRIDE];
            #pragma unroll
            for (int n = 0; n < NDIM; ++n) {
                const float4 w0 = *(const float4*)&wb[n * MDIM + 0];
                const float4 w1 = *(const float4*)&wb[n * MDIM + 4];
                const float4 w2 = *(const float4*)&wb[n * MDIM + 8];
                const float4 w3 = *(const float4*)&wb[n * MDIM + 12];
                const float xn = xs[n];
                u[0]  += xn * w0.x; u[1]  += xn * w0.y; u[2]  += xn * w0.z; u[3]  += xn * w0.w;
                u[4]  += xn * w1.x; u[5]  += xn * w1.y; u[6]  += xn * w1.z; u[7]  += xn * w1.w;
                u[8]  += xn * w2.x; u[9]  += xn * w2.y; u[10] += xn * w2.z; u[11] += xn * w2.w;
                u[12] += xn * w3.x; u[13] += xn * w3.y; u[14] += xn * w3.z; u[15] += xn * w3.w;
            }

            if (MODE == 0) {
                #pragma unroll
                for (int m = 0; m < MDIM; ++m) s[m] += u[m];
            } else {
                // in-register logit dot over m (4 parallel FMA chains)
                float la = v[0] * u[0],  lb = v[1] * u[1];
                float lc = v[2] * u[2],  ld = v[3] * u[3];
                la += v[4]  * u[4];  lb += v[5]  * u[5];
                lc += v[6]  * u[6];  ld += v[7]  * u[7];
                la += v[8]  * u[8];  lb += v[9]  * u[9];
                lc += v[10] * u[10]; ld += v[11] * u[11];
                la += v[12] * u[12]; lb += v[13] * u[13];
                lc += v[14] * u[14]; ld += v[15] * u[15];
                const float lp = (la + lb) + (lc + ld);
                // softmax over the 8 j-lanes (bits 0-2). |logit| small -> no max.
                const float e = __expf(lp);
                float d = e;
                d += __shfl_xor(d, 1);
                d += __shfl_xor(d, 2);
                d += __shfl_xor(d, 4);
                const float c = e * __builtin_amdgcn_rcpf(d);
                #pragma unroll
                for (int m = 0; m < MDIM; ++m) s[m] += c * u[m];
            }
        }
        __syncthreads();
    }

    // ---- combine i-parity halves via LDS (Wlds reuse is safe: synced) ----
    float* red = Wlds;                       // 8192 floats = 32 KB
    if (isub == 1) {
        #pragma unroll
        for (int q = 0; q < 4; ++q) {
            float4 o;
            o.x = s[q * 4 + 0]; o.y = s[q * 4 + 1];
            o.z = s[q * 4 + 2]; o.w = s[q * 4 + 3];
            *(float4*)&red[(b * JCAPS + j) * MDIM + q * 4] = o;
        }
    }
    __syncthreads();
    if (isub == 0) {
        const float sc = (MODE == 0) ? 0.125f : 1.0f;
        float* pp = partial + (size_t)blk * S_ELEMS + (b * JCAPS + j) * MDIM;
        #pragma unroll
        for (int q = 0; q < 4; ++q) {
            const float4 r = *(const float4*)&red[(b * JCAPS + j) * MDIM + q * 4];
            float4 o;
            o.x = (s[q * 4 + 0] + r.x) * sc; o.y = (s[q * 4 + 1] + r.y) * sc;
            o.z = (s[q * 4 + 2] + r.z) * sc; o.w = (s[q * 4 + 3] + r.w) * sc;
            *(float4*)&pp[q * 4] = o;
        }
    }
}

// Sum 256 partials -> s[b,j,m]; v = squash(s).
// OP 0: vsum = v (first pass, avoids memset)   OP 1: vsum += v   OP 2: out = v
template <int OP>
__global__ __launch_bounds__(256) void caps_reduce_kernel(
    const float* __restrict__ partial, float* __restrict__ vsum, float* __restrict__ out)
{
    __shared__ float sd[256];
    const int bo  = blockIdx.x;     // 0..127, each block covers 64 outputs
    const int tid = threadIdx.x;
    const int kg  = tid >> 6;       // 0..3  partial-group (64 partials each)
    const int tl  = tid & 63;       // output-within-block; lanes contiguous in t
    const int t   = bo * 64 + tl;   // global output index (= b*128 + j*16 + m)

    float a0 = 0.f, a1 = 0.f, a2 = 0.f, a3 = 0.f;
    const float* p = partial + (size_t)kg * 64 * S_ELEMS + t;
    #pragma unroll
    for (int k = 0; k < 64; k += 4) {
        a0 += p[(size_t)(k + 0) * S_ELEMS];
        a1 += p[(size_t)(k + 1) * S_ELEMS];
        a2 += p[(size_t)(k + 2) * S_ELEMS];
        a3 += p[(size_t)(k + 3) * S_ELEMS];
    }
    sd[tid] = (a0 + a1) + (a2 + a3);
    __syncthreads();

    if (tid < 64) {
        const float s = (sd[tid] + sd[64 + tid]) + (sd[128 + tid] + sd[192 + tid]);
        // squash: sn over the 16 m's of this (b,j) — lanes grouped by 16
        float sn = s * s;
        sn += __shfl_xor(sn, 1);
        sn += __shfl_xor(sn, 2);
        sn += __shfl_xor(sn, 4);
        sn += __shfl_xor(sn, 8);
        const float v = s * sqrtf(sn) / (1.f + sn);
        const int tt = bo * 64 + tid;
        if (OP == 2)      out[tt]   = v;
        else if (OP == 1) vsum[tt] += v;
        else              vsum[tt]  = v;
    }
}

extern "C" void kernel_launch(void* const* d_in, const int* in_sizes, int n_in,
                              void* d_out, int out_size, void* d_ws, size_t ws_size,
                              hipStream_t stream)
{
    const float* x = (const float*)d_in[0];   // [64, 8192, 8]
    const float* W = (const float*)d_in[1];   // [8192, 8, 8, 16]
    float* out = (float*)d_out;               // [64, 8, 16]

    float* partial = (float*)d_ws;                              // 256 * 8192 floats = 8 MB
    float* vsum    = partial + (size_t)NBLK * S_ELEMS;          // 8192 floats

    // pass 1: c uniform
    caps_pass_kernel<0><<<NBLK, 1024, 0, stream>>>(x, W, vsum, partial);
    caps_reduce_kernel<0><<<128, 256, 0, stream>>>(partial, vsum, nullptr);  // vsum = v1
    // pass 2: logits = dot(v1, u_hat)
    caps_pass_kernel<1><<<NBLK, 1024, 0, stream>>>(x, W, vsum, partial);
    caps_reduce_kernel<1><<<128, 256, 0, stream>>>(partial, vsum, nullptr);  // vsum = v1+v2
    // pass 3 (final): logits = dot(v1+v2, u_hat), output squash
    caps_pass_kernel<1><<<NBLK, 1024, 0, stream>>>(x, W, vsum, partial);
    caps_reduce_kernel<2><<<128, 256, 0, stream>>>(partial, vsum, out);
}